// Round 11
// baseline (308.509 us; speedup 1.0000x reference)
//
#include <hip/hip_runtime.h>
#include <hip/hip_fp16.h>

#define NDIM 64
#define RS 68      // LDS row stride in floats: 16B-aligned rows
#define MAXNB 512  // supports N <= 131072 (bucket = dst>>8); this problem: N=100000 -> 391
#define CAP 6144   // padded per-bucket capacity (expected ~3072, +55 sigma headroom)
#define EBUF 704   // per-wave LDS edge-index buffer (32 rows, mean 384 edges, +16 sigma)

typedef _Float16 h4 __attribute__((ext_vector_type(4)));
typedef float f4v __attribute__((ext_vector_type(4)));

// ---------------- prep: BN-fold + split-fp16 weight pack, x -> fp16, bcnt zero ----------------
// Wpk layout: [(l*2+m)][frag=ks*4+ct][lane][0..3]=hi j, [4..7]=lo j (halfs)
// frag element: k = ks*16 + (lane>>4)*4 + j, col = ct*16 + (lane&15)
__global__ __launch_bounds__(256) void prep_kernel(
    const float* __restrict__ x, __half* __restrict__ x16, int n4,
    const float* __restrict__ W1, const float* __restrict__ b1,
    const float* __restrict__ gamma, const float* __restrict__ beta,
    const float* __restrict__ mean, const float* __restrict__ var,
    const float* __restrict__ W2,
    _Float16* __restrict__ Wpk, float* __restrict__ b1f, int L,
    int* __restrict__ bcnt, int nbz)
{
    int bid = blockIdx.x;
    int t = threadIdx.x;
    if (bid < 2 * L) {
        if (bid == 0)
            for (int i = t; i < nbz; i += 256) bcnt[i] = 0;   // replaces hipMemsetAsync
        int l = bid >> 1, m = bid & 1;
        const float* Wsrc = (m == 0 ? W1 : W2) + (size_t)l * 4096;
        if (m == 0 && t < 64) {
            float s = gamma[l * 64 + t] * rsqrtf(var[l * 64 + t] + 1e-5f);
            b1f[l * 64 + t] = (b1[l * 64 + t] - mean[l * 64 + t]) * s + beta[l * 64 + t];
        }
        int lane = t & 63;
        int c16 = lane & 15, kq = lane >> 4;
        for (int it = 0; it < 4; ++it) {
            int frag = it * 4 + (t >> 6);
            int ks = frag >> 2, ct = frag & 3;
            int col = ct * 16 + c16;
            int k0 = ks * 16 + kq * 4;
            float s = 1.f;
            if (m == 0) s = gamma[l * 64 + col] * rsqrtf(var[l * 64 + col] + 1e-5f);
            _Float16* dstp = Wpk + (((size_t)(l * 2 + m) * 16 + frag) * 64 + lane) * 8;
            for (int j = 0; j < 4; ++j) {
                float wv = Wsrc[(size_t)(k0 + j) * 64 + col] * s;
                _Float16 hi = (_Float16)wv;
                dstp[j] = hi;
                dstp[4 + j] = (_Float16)(wv - (float)hi);
            }
        }
        return;
    }
    int tid = (bid - 2 * L) * 256 + t;
    if (tid >= n4) return;
    float4 v = *(const float4*)(x + (size_t)tid * 4);
    __half2* dp = (__half2*)(x16 + (size_t)tid * 4);
    dp[0] = __floats2half2_rn(v.x, v.y);
    dp[1] = __floats2half2_rn(v.z, v.w);
}

// ---------------- single-pass bucket scatter into padded regions ----------------
__global__ __launch_bounds__(256) void bucket_scatter_kernel(
    const int* __restrict__ src, const int* __restrict__ dst,
    int* __restrict__ bcnt, unsigned int* __restrict__ packed, int E, int NBb)
{
    __shared__ int hist[MAXNB];
    __shared__ int sbase[MAXNB];
    for (int i = threadIdx.x; i < NBb; i += 256) hist[i] = 0;
    __syncthreads();
    int start = blockIdx.x * blockDim.x + threadIdx.x;
    int stride = gridDim.x * blockDim.x;
    for (int e = start; e < E; e += stride)
        atomicAdd(&hist[dst[e] >> 8], 1);          // LDS int atomic: native, on-CU
    __syncthreads();
    for (int i = threadIdx.x; i < NBb; i += 256) {
        int v = hist[i];
        sbase[i] = v ? (i * CAP + atomicAdd(&bcnt[i], v)) : 0;
    }
    __syncthreads();
    for (int i = threadIdx.x; i < NBb; i += 256) hist[i] = 0;  // reuse as cursor
    __syncthreads();
    for (int e = start; e < E; e += stride) {
        int d = dst[e];
        int b = d >> 8;
        int r = atomicAdd(&hist[b], 1);            // LDS rank
        packed[sbase[b] + r] = (unsigned)src[e] | ((unsigned)(d & 255) << 24);
    }
}

// ---------------- per-bucket CSR finalize (inline exclusive prefix of bcnt) ----------------
__global__ __launch_bounds__(256) void bucket_csr_kernel(
    const unsigned int* __restrict__ packed, const int* __restrict__ bcnt,
    int* __restrict__ ssrc, int* __restrict__ offs, int* __restrict__ ends, int N)
{
    __shared__ int hist[256], scan[256], cur[256];
    __shared__ int swbase;
    int b = blockIdx.x;
    int t = threadIdx.x;
    // exclusive prefix: wbase = sum_{i<b} bcnt[i]
    int partial = 0;
    for (int i = t; i < b; i += 256) partial += bcnt[i];
    scan[t] = partial;
    hist[t] = 0;
    __syncthreads();
    for (int d = 128; d > 0; d >>= 1) {
        if (t < d) scan[t] += scan[t + d];
        __syncthreads();
    }
    if (t == 0) swbase = scan[0];
    __syncthreads();
    int wbase = swbase;
    int cnt = bcnt[b];
    if (cnt > CAP) cnt = CAP;
    size_t rbase = (size_t)b * CAP;
    for (int i = t; i < cnt; i += 256)
        atomicAdd(&hist[packed[rbase + i] >> 24], 1);
    __syncthreads();
    int v = hist[t];
    scan[t] = v;
    __syncthreads();
    for (int d = 1; d < 256; d <<= 1) {
        int x = scan[t];
        int y = (t >= d) ? scan[t - d] : 0;
        __syncthreads();
        scan[t] = x + y;
        __syncthreads();
    }
    int e0 = wbase + scan[t] - v;
    cur[t] = e0;
    int node = b * 256 + t;
    if (node < N) { offs[node] = e0; ends[node] = e0 + v; }
    __syncthreads();
    for (int i = t; i < cnt; i += 256) {
        unsigned p = packed[rbase + i];
        int pos = atomicAdd(&cur[p >> 24], 1);
        ssrc[pos] = (int)(p & 0xFFFFFF);
    }
}

// ---- fused GIN layer: 1 wave per block, wave owns 32 rows (2x16 gather phases) ----
// r6-r9 lesson: occupancy 28-41% all give ~40-43us -> gather is service-rate-bound.
// This round halves the OTHER traffic: 32 rows/wave halves per-row weight re-reads
// (each wave reads 32KB of packed W; 3125 waves instead of 6250 -> 100MB vs 200MB).
__device__ inline void add4(float4& a, const float4& v) {
    a.x += v.x; a.y += v.y; a.z += v.z; a.w += v.w;
}

// accumulate 8 halves (16B) into two float4 accumulators
__device__ inline void cvt_acc(uint4 u, float4& a0, float4& a1) {
    __half2 h0 = __builtin_bit_cast(__half2, u.x);
    __half2 h1 = __builtin_bit_cast(__half2, u.y);
    __half2 h2 = __builtin_bit_cast(__half2, u.z);
    __half2 h3 = __builtin_bit_cast(__half2, u.w);
    float2 f0 = __half22float2(h0), f1 = __half22float2(h1);
    float2 f2 = __half22float2(h2), f3 = __half22float2(h3);
    a0.x += f0.x; a0.y += f0.y; a0.z += f1.x; a0.w += f1.y;
    a1.x += f2.x; a1.y += f2.y; a1.z += f3.x; a1.w += f3.y;
}

__global__ __launch_bounds__(64, 6) void gin_layer_kernel(
    const __half* __restrict__ hin, __half* __restrict__ hout,
    float* __restrict__ jk, const __half* __restrict__ hbase,
    const int* __restrict__ offs, const int* __restrict__ ends,
    const int* __restrict__ ssrc,
    const _Float16* __restrict__ w1p, const _Float16* __restrict__ w2p,
    const float* __restrict__ b1f, const float* __restrict__ b2,
    int N, int L, int relu_out, int last)
{
    __shared__ float wtile[32 * RS];     // 8704B: 32-row tile, reused pre->z->h
    __shared__ int ebuf[EBUF];           // 2816B: edge-index prefetch
    int lane = threadIdx.x;
    int wrow0 = blockIdx.x * 32;         // this wave's 32 rows
    if (wrow0 >= N) return;              // no barriers anywhere in this kernel

    // ---- CSR offsets via shuffle broadcast (no sync) ----
    int offv = 0, endv = 0;
    if (lane < 32) {
        int node = wrow0 + lane;
        int cn = (node < N) ? node : (N - 1);
        offv = offs[cn];
        endv = ends[cn];
        if (node >= N) offv = endv;      // OOB rows -> empty
    }
    int begAll = __shfl(offv, 0, 64);
    int endAll = __shfl(endv, 31, 64);
    int cnt = endAll - begAll;

    // ---- prefetch this wave's contiguous edge-index slice into LDS (coalesced) ----
    bool useLds = (cnt <= EBUF);
    if (useLds) {
        for (int k = lane; k < cnt; k += 64) ebuf[k] = ssrc[begAll + k];
    }
    asm volatile("" ::: "memory");       // compiler fence; same-wave DS is in-order in HW
    auto eidx = [&](int pos) -> int {
        return useLds ? ebuf[pos - begAll] : ssrc[pos];
    };

    // ---- gather: two sequential 16-row phases (same accumulators -> VGPR flat) ----
    int rslot = lane >> 3;   // 0..7
    int q = lane & 7;        // 16B chunk of the 128B row (8 halves)
    auto gather_pair = [&](int rselA, int rselB) {
        int nodeA = wrow0 + rselA;
        int nodeB = wrow0 + rselB;
        int begA = __shfl(offv, rselA, 64), endA = __shfl(endv, rselA, 64);
        int begB = __shfl(offv, rselB, 64), endB = __shfl(endv, rselB, 64);

        float4 a0 = make_float4(0.f, 0.f, 0.f, 0.f);
        float4 a1 = make_float4(0.f, 0.f, 0.f, 0.f);
        float4 c0 = make_float4(0.f, 0.f, 0.f, 0.f);
        float4 c1 = make_float4(0.f, 0.f, 0.f, 0.f);
        if (nodeA < N) {
            uint4 u = *(const uint4*)(hin + (size_t)nodeA * NDIM + q * 8);
            cvt_acc(u, a0, a1);
        }
        if (nodeB < N) {
            uint4 u = *(const uint4*)(hin + (size_t)nodeB * NDIM + q * 8);
            cvt_acc(u, c0, c1);
        }
        int kA = begA, kB = begB;
        while (kA + 4 <= endA && kB + 4 <= endB) {
            int iA0 = eidx(kA), iA1 = eidx(kA + 1), iA2 = eidx(kA + 2), iA3 = eidx(kA + 3);
            int iB0 = eidx(kB), iB1 = eidx(kB + 1), iB2 = eidx(kB + 2), iB3 = eidx(kB + 3);
            uint4 uA0 = *(const uint4*)(hin + (size_t)iA0 * NDIM + q * 8);
            uint4 uA1 = *(const uint4*)(hin + (size_t)iA1 * NDIM + q * 8);
            uint4 uA2 = *(const uint4*)(hin + (size_t)iA2 * NDIM + q * 8);
            uint4 uA3 = *(const uint4*)(hin + (size_t)iA3 * NDIM + q * 8);
            uint4 uB0 = *(const uint4*)(hin + (size_t)iB0 * NDIM + q * 8);
            uint4 uB1 = *(const uint4*)(hin + (size_t)iB1 * NDIM + q * 8);
            uint4 uB2 = *(const uint4*)(hin + (size_t)iB2 * NDIM + q * 8);
            uint4 uB3 = *(const uint4*)(hin + (size_t)iB3 * NDIM + q * 8);
            cvt_acc(uA0, a0, a1); cvt_acc(uA1, a0, a1);
            cvt_acc(uA2, a0, a1); cvt_acc(uA3, a0, a1);
            cvt_acc(uB0, c0, c1); cvt_acc(uB1, c0, c1);
            cvt_acc(uB2, c0, c1); cvt_acc(uB3, c0, c1);
            kA += 4; kB += 4;
        }
        for (; kA + 2 <= endA; kA += 2) {
            int i0 = eidx(kA), i1 = eidx(kA + 1);
            uint4 u0 = *(const uint4*)(hin + (size_t)i0 * NDIM + q * 8);
            uint4 u1 = *(const uint4*)(hin + (size_t)i1 * NDIM + q * 8);
            cvt_acc(u0, a0, a1);
            cvt_acc(u1, a0, a1);
        }
        if (kA < endA) {
            uint4 u = *(const uint4*)(hin + (size_t)eidx(kA) * NDIM + q * 8);
            cvt_acc(u, a0, a1);
        }
        for (; kB + 2 <= endB; kB += 2) {
            int i0 = eidx(kB), i1 = eidx(kB + 1);
            uint4 u0 = *(const uint4*)(hin + (size_t)i0 * NDIM + q * 8);
            uint4 u1 = *(const uint4*)(hin + (size_t)i1 * NDIM + q * 8);
            cvt_acc(u0, c0, c1);
            cvt_acc(u1, c0, c1);
        }
        if (kB < endB) {
            uint4 u = *(const uint4*)(hin + (size_t)eidx(kB) * NDIM + q * 8);
            cvt_acc(u, c0, c1);
        }
        if (nodeA < N) {
            float* p = wtile + rselA * RS + q * 8;
            *(float4*)(p) = a0;
            *(float4*)(p + 4) = a1;
        }
        if (nodeB < N) {
            float* p = wtile + rselB * RS + q * 8;
            *(float4*)(p) = c0;
            *(float4*)(p + 4) = c1;
        }
    };
    gather_pair(rslot, 8 + rslot);           // rows 0..15
    gather_pair(16 + rslot, 24 + rslot);     // rows 16..31
    asm volatile("" ::: "memory");   // phase fence (same-wave DS is in-order in HW)

    // ---- MLP via MFMA over TWO 16-row M-tiles, B fragments loaded once ----
    // A: row=lane&15 (+16 for tile1), k=4*(lane>>4)+j (+16*ks); B: col=lane&15, same k
    // C: row=(lane>>4)*4+reg, col=lane&15
    int lane15 = lane & 15;
    int lgrp = lane >> 4;
    const float* aRow0 = wtile + (size_t)lane15 * RS;
    const float* aRow1 = wtile + (size_t)(16 + lane15) * RS;
    const h4* W1 = (const h4*)w1p;
    const h4* W2 = (const h4*)w2p;
    f4v zero = {0.f, 0.f, 0.f, 0.f};
    f4v acc0[4], acc1[4];

    // GEMM1: z = relu(pre @ W1f + b1f)
    #pragma unroll
    for (int ct = 0; ct < 4; ++ct) { acc0[ct] = zero; acc1[ct] = zero; }
    #pragma unroll
    for (int ks = 0; ks < 4; ++ks) {
        float4 av0 = *(const float4*)(aRow0 + ks * 16 + lgrp * 4);
        float4 av1 = *(const float4*)(aRow1 + ks * 16 + lgrp * 4);
        h4 ah0, al0, ah1, al1;
        ah0[0] = (_Float16)av0.x; al0[0] = (_Float16)(av0.x - (float)ah0[0]);
        ah0[1] = (_Float16)av0.y; al0[1] = (_Float16)(av0.y - (float)ah0[1]);
        ah0[2] = (_Float16)av0.z; al0[2] = (_Float16)(av0.z - (float)ah0[2]);
        ah0[3] = (_Float16)av0.w; al0[3] = (_Float16)(av0.w - (float)ah0[3]);
        ah1[0] = (_Float16)av1.x; al1[0] = (_Float16)(av1.x - (float)ah1[0]);
        ah1[1] = (_Float16)av1.y; al1[1] = (_Float16)(av1.y - (float)ah1[1]);
        ah1[2] = (_Float16)av1.z; al1[2] = (_Float16)(av1.z - (float)ah1[2]);
        ah1[3] = (_Float16)av1.w; al1[3] = (_Float16)(av1.w - (float)ah1[3]);
        #pragma unroll
        for (int ct = 0; ct < 4; ++ct) {
            const h4* bp = W1 + (size_t)((ks * 4 + ct) * 64 + lane) * 2;
            h4 bh = bp[0], bl = bp[1];   // one dwordx4, reused by both tiles
            acc0[ct] = __builtin_amdgcn_mfma_f32_16x16x16f16(ah0, bh, acc0[ct], 0, 0, 0);
            acc0[ct] = __builtin_amdgcn_mfma_f32_16x16x16f16(al0, bh, acc0[ct], 0, 0, 0);
            acc0[ct] = __builtin_amdgcn_mfma_f32_16x16x16f16(ah0, bl, acc0[ct], 0, 0, 0);
            acc1[ct] = __builtin_amdgcn_mfma_f32_16x16x16f16(ah1, bh, acc1[ct], 0, 0, 0);
            acc1[ct] = __builtin_amdgcn_mfma_f32_16x16x16f16(al1, bh, acc1[ct], 0, 0, 0);
            acc1[ct] = __builtin_amdgcn_mfma_f32_16x16x16f16(ah1, bl, acc1[ct], 0, 0, 0);
        }
    }
    asm volatile("" ::: "memory");
    #pragma unroll
    for (int ct = 0; ct < 4; ++ct) {
        int col = ct * 16 + lane15;
        float bb = b1f[col];
        #pragma unroll
        for (int i = 0; i < 4; ++i) {
            wtile[(size_t)(lgrp * 4 + i) * RS + col] = fmaxf(acc0[ct][i] + bb, 0.f);
            wtile[(size_t)(16 + lgrp * 4 + i) * RS + col] = fmaxf(acc1[ct][i] + bb, 0.f);
        }
    }
    asm volatile("" ::: "memory");

    // GEMM2: h = z @ W2 + b2 (+relu for non-final layers)
    #pragma unroll
    for (int ct = 0; ct < 4; ++ct) { acc0[ct] = zero; acc1[ct] = zero; }
    #pragma unroll
    for (int ks = 0; ks < 4; ++ks) {
        float4 av0 = *(const float4*)(aRow0 + ks * 16 + lgrp * 4);
        float4 av1 = *(const float4*)(aRow1 + ks * 16 + lgrp * 4);
        h4 ah0, al0, ah1, al1;
        ah0[0] = (_Float16)av0.x; al0[0] = (_Float16)(av0.x - (float)ah0[0]);
        ah0[1] = (_Float16)av0.y; al0[1] = (_Float16)(av0.y - (float)ah0[1]);
        ah0[2] = (_Float16)av0.z; al0[2] = (_Float16)(av0.z - (float)ah0[2]);
        ah0[3] = (_Float16)av0.w; al0[3] = (_Float16)(av0.w - (float)ah0[3]);
        ah1[0] = (_Float16)av1.x; al1[0] = (_Float16)(av1.x - (float)ah1[0]);
        ah1[1] = (_Float16)av1.y; al1[1] = (_Float16)(av1.y - (float)ah1[1]);
        ah1[2] = (_Float16)av1.z; al1[2] = (_Float16)(av1.z - (float)ah1[2]);
        ah1[3] = (_Float16)av1.w; al1[3] = (_Float16)(av1.w - (float)ah1[3]);
        #pragma unroll
        for (int ct = 0; ct < 4; ++ct) {
            const h4* bp = W2 + (size_t)((ks * 4 + ct) * 64 + lane) * 2;
            h4 bh = bp[0], bl = bp[1];
            acc0[ct] = __builtin_amdgcn_mfma_f32_16x16x16f16(ah0, bh, acc0[ct], 0, 0, 0);
            acc0[ct] = __builtin_amdgcn_mfma_f32_16x16x16f16(al0, bh, acc0[ct], 0, 0, 0);
            acc0[ct] = __builtin_amdgcn_mfma_f32_16x16x16f16(ah0, bl, acc0[ct], 0, 0, 0);
            acc1[ct] = __builtin_amdgcn_mfma_f32_16x16x16f16(ah1, bh, acc1[ct], 0, 0, 0);
            acc1[ct] = __builtin_amdgcn_mfma_f32_16x16x16f16(al1, bh, acc1[ct], 0, 0, 0);
            acc1[ct] = __builtin_amdgcn_mfma_f32_16x16x16f16(ah1, bl, acc1[ct], 0, 0, 0);
        }
    }
    asm volatile("" ::: "memory");
    #pragma unroll
    for (int ct = 0; ct < 4; ++ct) {
        int col = ct * 16 + lane15;
        float bb = b2[col];
        #pragma unroll
        for (int i = 0; i < 4; ++i) {
            float hv0 = acc0[ct][i] + bb;
            float hv1 = acc1[ct][i] + bb;
            if (relu_out) { hv0 = fmaxf(hv0, 0.f); hv1 = fmaxf(hv1, 0.f); }
            wtile[(size_t)(lgrp * 4 + i) * RS + col] = hv0;
            wtile[(size_t)(16 + lgrp * 4 + i) * RS + col] = hv1;
        }
    }
    asm volatile("" ::: "memory");

    // ---- writeback ----
    // non-last layers: h -> fp16 buffer only (jk never touched).
    // last layer: jk = h_L + sum_{j=1..L-1} h_j (read back from fp16 buffers, L2/L3-warm).
    size_t nstride = (size_t)N * NDIM;
    #pragma unroll
    for (int it = 0; it < 8; ++it) {
        int fl = it * 64 + lane;
        int r = fl >> 4, c4 = fl & 15;
        int grow = wrow0 + r;
        if (grow >= N) continue;
        const float* p = wtile + (size_t)r * RS + c4 * 4;
        float4 hv = make_float4(p[0], p[1], p[2], p[3]);
        if (!last) {
            __half2* dp = (__half2*)(hout + (size_t)grow * NDIM + c4 * 4);
            dp[0] = __floats2half2_rn(hv.x, hv.y);
            dp[1] = __floats2half2_rn(hv.z, hv.w);
        } else {
            for (int j = 1; j < L; ++j) {
                uint2 u = *(const uint2*)(hbase + (size_t)j * nstride
                                          + (size_t)grow * NDIM + c4 * 4);
                __half2 x0 = __builtin_bit_cast(__half2, u.x);
                __half2 x1 = __builtin_bit_cast(__half2, u.y);
                float2 f0 = __half22float2(x0), f1 = __half22float2(x1);
                hv.x += f0.x; hv.y += f0.y; hv.z += f1.x; hv.w += f1.y;
            }
            *(float4*)(jk + (size_t)grow * NDIM + c4 * 4) = hv;
        }
    }
}

extern "C" void kernel_launch(void* const* d_in, const int* in_sizes, int n_in,
                              void* d_out, int out_size, void* d_ws, size_t ws_size,
                              hipStream_t stream) {
    const float* x     = (const float*)d_in[0];
    const int*   src   = (const int*)  d_in[1];
    const int*   dst   = (const int*)  d_in[2];
    const float* W1    = (const float*)d_in[3];
    const float* b1    = (const float*)d_in[4];
    const float* gamma = (const float*)d_in[5];
    const float* beta  = (const float*)d_in[6];
    const float* mean  = (const float*)d_in[7];
    const float* var   = (const float*)d_in[8];
    const float* W2    = (const float*)d_in[9];
    const float* b2    = (const float*)d_in[10];

    int N = in_sizes[0] / NDIM;
    int E = in_sizes[1];
    int L = in_sizes[3] / (NDIM * NDIM);
    int NBb = (N + 255) >> 8;            // buckets of 256 nodes
    int n4 = N * NDIM / 4;
    float* out = (float*)d_out;
    size_t ns = (size_t)N * NDIM;

    char* w = (char*)d_ws;
    size_t off = 0;
    auto carve = [&](size_t bytes) -> void* {
        void* p = w + off;
        off += (bytes + 255) & ~(size_t)255;
        return p;
    };
    __half* h16     = (__half*)carve((size_t)(L + 1) * ns * 2);  // x16, h1..hL chain
    int*    ssrc    = (int*)   carve((size_t)E * 4);
    unsigned int* packed = (unsigned int*)carve((size_t)NBb * CAP * 4);
    int*    offs    = (int*)   carve((size_t)N * 4);
    int*    ends    = (int*)   carve((size_t)N * 4);
    int*    bcnt    = (int*)   carve((size_t)(MAXNB + 1) * 4);
    _Float16* Wpk   = (_Float16*)carve((size_t)L * 2 * 16 * 64 * 8 * 2);  // hi/lo packed frags
    float*  b1f     = (float*) carve((size_t)L * NDIM * 4);

    prep_kernel<<<2 * L + (n4 + 255) / 256, 256, 0, stream>>>(
        x, h16, n4, W1, b1, gamma, beta, mean, var, W2, Wpk, b1f, L,
        bcnt, NBb + 1);
    bucket_scatter_kernel<<<256, 256, 0, stream>>>(src, dst, bcnt, packed, E, NBb);
    bucket_csr_kernel<<<NBb, 256, 0, stream>>>(packed, bcnt, ssrc, offs, ends, N);

    int NB32 = (N + 31) / 32;
    for (int l = 0; l < L; ++l) {
        gin_layer_kernel<<<NB32, 64, 0, stream>>>(
            h16 + (size_t)l * ns, h16 + (size_t)(l + 1) * ns, out, h16,
            offs, ends, ssrc,
            Wpk + (size_t)(l * 2 + 0) * 16 * 64 * 8,
            Wpk + (size_t)(l * 2 + 1) * 16 * 64 * 8,
            b1f + (size_t)l * NDIM, b2 + (size_t)l * NDIM,
            N, L, (l < L - 1) ? 1 : 0, (l == L - 1) ? 1 : 0);
    }
}

// Round 12
// 236.012 us; speedup vs baseline: 1.3072x; 1.3072x over previous
//
#include <hip/hip_runtime.h>
#include <hip/hip_fp16.h>

#define NDIM 64
#define RS 68      // LDS row stride in floats: 16B-aligned rows
#define MAXNB 512  // supports N <= 131072 (bucket = dst>>8); this problem: N=100000 -> 391
#define CAP 6144   // padded per-bucket capacity (expected ~3072, +55 sigma headroom)
#define EBUF 352   // per-block LDS edge-index buffer (16 rows, mean 192 edges, +11 sigma)

typedef _Float16 h4 __attribute__((ext_vector_type(4)));
typedef float f4v __attribute__((ext_vector_type(4)));

// ---------------- prep: BN-fold + split-fp16 weight pack, x -> fp16, bcnt zero ----------------
// Wpk layout: [(l*2+m)][frag=ks*4+ct][lane][0..3]=hi j, [4..7]=lo j (halfs)
// frag element: k = ks*16 + (lane>>4)*4 + j, col = ct*16 + (lane&15)
__global__ __launch_bounds__(256) void prep_kernel(
    const float* __restrict__ x, __half* __restrict__ x16, int n4,
    const float* __restrict__ W1, const float* __restrict__ b1,
    const float* __restrict__ gamma, const float* __restrict__ beta,
    const float* __restrict__ mean, const float* __restrict__ var,
    const float* __restrict__ W2,
    _Float16* __restrict__ Wpk, float* __restrict__ b1f, int L,
    int* __restrict__ bcnt, int nbz)
{
    int bid = blockIdx.x;
    int t = threadIdx.x;
    if (bid < 2 * L) {
        if (bid == 0)
            for (int i = t; i < nbz; i += 256) bcnt[i] = 0;   // replaces hipMemsetAsync
        int l = bid >> 1, m = bid & 1;
        const float* Wsrc = (m == 0 ? W1 : W2) + (size_t)l * 4096;
        if (m == 0 && t < 64) {
            float s = gamma[l * 64 + t] * rsqrtf(var[l * 64 + t] + 1e-5f);
            b1f[l * 64 + t] = (b1[l * 64 + t] - mean[l * 64 + t]) * s + beta[l * 64 + t];
        }
        int lane = t & 63;
        int c16 = lane & 15, kq = lane >> 4;
        for (int it = 0; it < 4; ++it) {
            int frag = it * 4 + (t >> 6);
            int ks = frag >> 2, ct = frag & 3;
            int col = ct * 16 + c16;
            int k0 = ks * 16 + kq * 4;
            float s = 1.f;
            if (m == 0) s = gamma[l * 64 + col] * rsqrtf(var[l * 64 + col] + 1e-5f);
            _Float16* dstp = Wpk + (((size_t)(l * 2 + m) * 16 + frag) * 64 + lane) * 8;
            for (int j = 0; j < 4; ++j) {
                float wv = Wsrc[(size_t)(k0 + j) * 64 + col] * s;
                _Float16 hi = (_Float16)wv;
                dstp[j] = hi;
                dstp[4 + j] = (_Float16)(wv - (float)hi);
            }
        }
        return;
    }
    int tid = (bid - 2 * L) * 256 + t;
    if (tid >= n4) return;
    float4 v = *(const float4*)(x + (size_t)tid * 4);
    __half2* dp = (__half2*)(x16 + (size_t)tid * 4);
    dp[0] = __floats2half2_rn(v.x, v.y);
    dp[1] = __floats2half2_rn(v.z, v.w);
}

// ---------------- single-pass bucket scatter into padded regions ----------------
__global__ __launch_bounds__(256) void bucket_scatter_kernel(
    const int* __restrict__ src, const int* __restrict__ dst,
    int* __restrict__ bcnt, unsigned int* __restrict__ packed, int E, int NBb)
{
    __shared__ int hist[MAXNB];
    __shared__ int sbase[MAXNB];
    for (int i = threadIdx.x; i < NBb; i += 256) hist[i] = 0;
    __syncthreads();
    int start = blockIdx.x * blockDim.x + threadIdx.x;
    int stride = gridDim.x * blockDim.x;
    for (int e = start; e < E; e += stride)
        atomicAdd(&hist[dst[e] >> 8], 1);          // LDS int atomic: native, on-CU
    __syncthreads();
    for (int i = threadIdx.x; i < NBb; i += 256) {
        int v = hist[i];
        sbase[i] = v ? (i * CAP + atomicAdd(&bcnt[i], v)) : 0;
    }
    __syncthreads();
    for (int i = threadIdx.x; i < NBb; i += 256) hist[i] = 0;  // reuse as cursor
    __syncthreads();
    for (int e = start; e < E; e += stride) {
        int d = dst[e];
        int b = d >> 8;
        int r = atomicAdd(&hist[b], 1);            // LDS rank
        packed[sbase[b] + r] = (unsigned)src[e] | ((unsigned)(d & 255) << 24);
    }
}

// ---------------- per-bucket CSR finalize (inline exclusive prefix of bcnt) ----------------
__global__ __launch_bounds__(256) void bucket_csr_kernel(
    const unsigned int* __restrict__ packed, const int* __restrict__ bcnt,
    int* __restrict__ ssrc, int* __restrict__ offs, int* __restrict__ ends, int N)
{
    __shared__ int hist[256], scan[256], cur[256];
    __shared__ int swbase;
    int b = blockIdx.x;
    int t = threadIdx.x;
    // exclusive prefix: wbase = sum_{i<b} bcnt[i]
    int partial = 0;
    for (int i = t; i < b; i += 256) partial += bcnt[i];
    scan[t] = partial;
    hist[t] = 0;
    __syncthreads();
    for (int d = 128; d > 0; d >>= 1) {
        if (t < d) scan[t] += scan[t + d];
        __syncthreads();
    }
    if (t == 0) swbase = scan[0];
    __syncthreads();
    int wbase = swbase;
    int cnt = bcnt[b];
    if (cnt > CAP) cnt = CAP;
    size_t rbase = (size_t)b * CAP;
    for (int i = t; i < cnt; i += 256)
        atomicAdd(&hist[packed[rbase + i] >> 24], 1);
    __syncthreads();
    int v = hist[t];
    scan[t] = v;
    __syncthreads();
    for (int d = 1; d < 256; d <<= 1) {
        int x = scan[t];
        int y = (t >= d) ? scan[t - d] : 0;
        __syncthreads();
        scan[t] = x + y;
        __syncthreads();
    }
    int e0 = wbase + scan[t] - v;
    cur[t] = e0;
    int node = b * 256 + t;
    if (node < N) { offs[node] = e0; ends[node] = e0 + v; }
    __syncthreads();
    for (int i = t; i < cnt; i += 256) {
        unsigned p = packed[rbase + i];
        int pos = atomicAdd(&cur[p >> 24], 1);
        ssrc[pos] = (int)(p & 0xFFFFFF);
    }
}

// ---------------- fused GIN layer: one wave per block, block owns 16 rows ----------------
// Best verified config (r7: 232.9us total). r6-r11 sweep: above ~28% occupancy the
// layer pins at 40-43us while L2-miss traffic pins at ~2TB/s -> L3 random-service
// floor (E x 128B logical, ~50% L2 miss on 12.8MB hin vs 4MB/XCD L2).
__device__ inline void add4(float4& a, const float4& v) {
    a.x += v.x; a.y += v.y; a.z += v.z; a.w += v.w;
}

// accumulate 8 halves (16B) into two float4 accumulators
__device__ inline void cvt_acc(uint4 u, float4& a0, float4& a1) {
    __half2 h0 = __builtin_bit_cast(__half2, u.x);
    __half2 h1 = __builtin_bit_cast(__half2, u.y);
    __half2 h2 = __builtin_bit_cast(__half2, u.z);
    __half2 h3 = __builtin_bit_cast(__half2, u.w);
    float2 f0 = __half22float2(h0), f1 = __half22float2(h1);
    float2 f2 = __half22float2(h2), f3 = __half22float2(h3);
    a0.x += f0.x; a0.y += f0.y; a0.z += f1.x; a0.w += f1.y;
    a1.x += f2.x; a1.y += f2.y; a1.z += f3.x; a1.w += f3.y;
}

__global__ __launch_bounds__(64, 7) void gin_layer_kernel(
    const __half* __restrict__ hin, __half* __restrict__ hout,
    float* __restrict__ jk, const __half* __restrict__ hbase,
    const int* __restrict__ offs, const int* __restrict__ ends,
    const int* __restrict__ ssrc,
    const _Float16* __restrict__ w1p, const _Float16* __restrict__ w2p,
    const float* __restrict__ b1f, const float* __restrict__ b2,
    int N, int L, int relu_out, int last)
{
    __shared__ float wtile[16 * RS];     // 4352B: 16-row tile, reused pre->z->h
    __shared__ int ebuf[EBUF];           // 1408B: edge-index prefetch
    int lane = threadIdx.x;
    int wrow0 = blockIdx.x * 16;         // this block's 16 rows
    if (wrow0 >= N) return;              // no barriers anywhere in this kernel

    // ---- CSR offsets via shuffle broadcast (no sync) ----
    int offv = 0, endv = 0;
    if (lane < 16) {
        int node = wrow0 + lane;
        int cn = (node < N) ? node : (N - 1);
        offv = offs[cn];
        endv = ends[cn];
        if (node >= N) offv = endv;      // OOB rows -> empty
    }
    int begAll = __shfl(offv, 0, 64);
    int endAll = __shfl(endv, 15, 64);
    int cnt = endAll - begAll;

    // ---- prefetch this block's contiguous edge-index slice into LDS (coalesced) ----
    bool useLds = (cnt <= EBUF);
    if (useLds) {
        for (int k = lane; k < cnt; k += 64) ebuf[k] = ssrc[begAll + k];
    }
    asm volatile("" ::: "memory");       // compiler fence; same-wave DS is in-order in HW
    auto eidx = [&](int pos) -> int {
        return useLds ? ebuf[pos - begAll] : ssrc[pos];
    };

    // ---- gather: 16 rows as 8 concurrent pairs; lane = (row-slot, 16B chunk) ----
    // 4-wide joint unroll: up to 8 independent edge loads in flight per lane.
    {
        int rslot = lane >> 3;   // 0..7
        int q = lane & 7;        // 16B chunk of the 128B row (8 halves)
        int nodeA = wrow0 + rslot;
        int nodeB = wrow0 + 8 + rslot;
        int begA = __shfl(offv, rslot, 64),     endA = __shfl(endv, rslot, 64);
        int begB = __shfl(offv, 8 + rslot, 64), endB = __shfl(endv, 8 + rslot, 64);

        float4 a0 = make_float4(0.f, 0.f, 0.f, 0.f);
        float4 a1 = make_float4(0.f, 0.f, 0.f, 0.f);
        float4 c0 = make_float4(0.f, 0.f, 0.f, 0.f);
        float4 c1 = make_float4(0.f, 0.f, 0.f, 0.f);
        if (nodeA < N) {
            uint4 u = *(const uint4*)(hin + (size_t)nodeA * NDIM + q * 8);
            cvt_acc(u, a0, a1);
        }
        if (nodeB < N) {
            uint4 u = *(const uint4*)(hin + (size_t)nodeB * NDIM + q * 8);
            cvt_acc(u, c0, c1);
        }
        int kA = begA, kB = begB;
        while (kA + 4 <= endA && kB + 4 <= endB) {
            int iA0 = eidx(kA), iA1 = eidx(kA + 1), iA2 = eidx(kA + 2), iA3 = eidx(kA + 3);
            int iB0 = eidx(kB), iB1 = eidx(kB + 1), iB2 = eidx(kB + 2), iB3 = eidx(kB + 3);
            uint4 uA0 = *(const uint4*)(hin + (size_t)iA0 * NDIM + q * 8);
            uint4 uA1 = *(const uint4*)(hin + (size_t)iA1 * NDIM + q * 8);
            uint4 uA2 = *(const uint4*)(hin + (size_t)iA2 * NDIM + q * 8);
            uint4 uA3 = *(const uint4*)(hin + (size_t)iA3 * NDIM + q * 8);
            uint4 uB0 = *(const uint4*)(hin + (size_t)iB0 * NDIM + q * 8);
            uint4 uB1 = *(const uint4*)(hin + (size_t)iB1 * NDIM + q * 8);
            uint4 uB2 = *(const uint4*)(hin + (size_t)iB2 * NDIM + q * 8);
            uint4 uB3 = *(const uint4*)(hin + (size_t)iB3 * NDIM + q * 8);
            cvt_acc(uA0, a0, a1); cvt_acc(uA1, a0, a1);
            cvt_acc(uA2, a0, a1); cvt_acc(uA3, a0, a1);
            cvt_acc(uB0, c0, c1); cvt_acc(uB1, c0, c1);
            cvt_acc(uB2, c0, c1); cvt_acc(uB3, c0, c1);
            kA += 4; kB += 4;
        }
        for (; kA + 2 <= endA; kA += 2) {
            int i0 = eidx(kA), i1 = eidx(kA + 1);
            uint4 u0 = *(const uint4*)(hin + (size_t)i0 * NDIM + q * 8);
            uint4 u1 = *(const uint4*)(hin + (size_t)i1 * NDIM + q * 8);
            cvt_acc(u0, a0, a1);
            cvt_acc(u1, a0, a1);
        }
        if (kA < endA) {
            uint4 u = *(const uint4*)(hin + (size_t)eidx(kA) * NDIM + q * 8);
            cvt_acc(u, a0, a1);
        }
        for (; kB + 2 <= endB; kB += 2) {
            int i0 = eidx(kB), i1 = eidx(kB + 1);
            uint4 u0 = *(const uint4*)(hin + (size_t)i0 * NDIM + q * 8);
            uint4 u1 = *(const uint4*)(hin + (size_t)i1 * NDIM + q * 8);
            cvt_acc(u0, c0, c1);
            cvt_acc(u1, c0, c1);
        }
        if (kB < endB) {
            uint4 u = *(const uint4*)(hin + (size_t)eidx(kB) * NDIM + q * 8);
            cvt_acc(u, c0, c1);
        }
        if (nodeA < N) {
            float* p = wtile + rslot * RS + q * 8;
            *(float4*)(p) = a0;
            *(float4*)(p + 4) = a1;
        }
        if (nodeB < N) {
            float* p = wtile + (8 + rslot) * RS + q * 8;
            *(float4*)(p) = c0;
            *(float4*)(p + 4) = c1;
        }
    }
    asm volatile("" ::: "memory");   // phase fence (same-wave DS is in-order in HW)

    // ---- MLP via MFMA, split-fp16 for ~fp32 accuracy ----
    // A: row=lane&15, k=4*(lane>>4)+j (+16*ks); B: col=lane&15, same k
    // C: row=(lane>>4)*4+reg, col=lane&15
    int lane15 = lane & 15;
    int lgrp = lane >> 4;
    const float* aRow = wtile + (size_t)lane15 * RS;
    const h4* W1 = (const h4*)w1p;
    const h4* W2 = (const h4*)w2p;
    f4v zero = {0.f, 0.f, 0.f, 0.f};
    f4v acc[4];

    // GEMM1: z = relu(pre @ W1f + b1f)
    #pragma unroll
    for (int ct = 0; ct < 4; ++ct) acc[ct] = zero;
    #pragma unroll
    for (int ks = 0; ks < 4; ++ks) {
        float4 av = *(const float4*)(aRow + ks * 16 + lgrp * 4);
        h4 ah, al;
        ah[0] = (_Float16)av.x; al[0] = (_Float16)(av.x - (float)ah[0]);
        ah[1] = (_Float16)av.y; al[1] = (_Float16)(av.y - (float)ah[1]);
        ah[2] = (_Float16)av.z; al[2] = (_Float16)(av.z - (float)ah[2]);
        ah[3] = (_Float16)av.w; al[3] = (_Float16)(av.w - (float)ah[3]);
        #pragma unroll
        for (int ct = 0; ct < 4; ++ct) {
            const h4* bp = W1 + (size_t)((ks * 4 + ct) * 64 + lane) * 2;
            h4 bh = bp[0], bl = bp[1];   // one dwordx4
            acc[ct] = __builtin_amdgcn_mfma_f32_16x16x16f16(ah, bh, acc[ct], 0, 0, 0);
            acc[ct] = __builtin_amdgcn_mfma_f32_16x16x16f16(al, bh, acc[ct], 0, 0, 0);
            acc[ct] = __builtin_amdgcn_mfma_f32_16x16x16f16(ah, bl, acc[ct], 0, 0, 0);
        }
    }
    asm volatile("" ::: "memory");
    #pragma unroll
    for (int ct = 0; ct < 4; ++ct) {
        int col = ct * 16 + lane15;
        float bb = b1f[col];
        #pragma unroll
        for (int i = 0; i < 4; ++i)
            wtile[(size_t)(lgrp * 4 + i) * RS + col] = fmaxf(acc[ct][i] + bb, 0.f);
    }
    asm volatile("" ::: "memory");

    // GEMM2: h = z @ W2 + b2 (+relu for non-final layers)
    #pragma unroll
    for (int ct = 0; ct < 4; ++ct) acc[ct] = zero;
    #pragma unroll
    for (int ks = 0; ks < 4; ++ks) {
        float4 av = *(const float4*)(aRow + ks * 16 + lgrp * 4);
        h4 ah, al;
        ah[0] = (_Float16)av.x; al[0] = (_Float16)(av.x - (float)ah[0]);
        ah[1] = (_Float16)av.y; al[1] = (_Float16)(av.y - (float)ah[1]);
        ah[2] = (_Float16)av.z; al[2] = (_Float16)(av.z - (float)ah[2]);
        ah[3] = (_Float16)av.w; al[3] = (_Float16)(av.w - (float)ah[3]);
        #pragma unroll
        for (int ct = 0; ct < 4; ++ct) {
            const h4* bp = W2 + (size_t)((ks * 4 + ct) * 64 + lane) * 2;
            h4 bh = bp[0], bl = bp[1];
            acc[ct] = __builtin_amdgcn_mfma_f32_16x16x16f16(ah, bh, acc[ct], 0, 0, 0);
            acc[ct] = __builtin_amdgcn_mfma_f32_16x16x16f16(al, bh, acc[ct], 0, 0, 0);
            acc[ct] = __builtin_amdgcn_mfma_f32_16x16x16f16(ah, bl, acc[ct], 0, 0, 0);
        }
    }
    asm volatile("" ::: "memory");
    #pragma unroll
    for (int ct = 0; ct < 4; ++ct) {
        int col = ct * 16 + lane15;
        float bb = b2[col];
        #pragma unroll
        for (int i = 0; i < 4; ++i) {
            float hv = acc[ct][i] + bb;
            if (relu_out) hv = fmaxf(hv, 0.f);
            wtile[(size_t)(lgrp * 4 + i) * RS + col] = hv;
        }
    }
    asm volatile("" ::: "memory");

    // ---- writeback ----
    // non-last layers: h -> fp16 buffer only (jk never touched).
    // last layer: jk = h_L + sum_{j=1..L-1} h_j (read back from fp16 buffers, L2/L3-warm).
    size_t nstride = (size_t)N * NDIM;
    #pragma unroll
    for (int it = 0; it < 4; ++it) {
        int fl = it * 64 + lane;
        int r = fl >> 4, c4 = fl & 15;
        int grow = wrow0 + r;
        if (grow >= N) continue;
        const float* p = wtile + (size_t)r * RS + c4 * 4;
        float4 hv = make_float4(p[0], p[1], p[2], p[3]);
        if (!last) {
            __half2* dp = (__half2*)(hout + (size_t)grow * NDIM + c4 * 4);
            dp[0] = __floats2half2_rn(hv.x, hv.y);
            dp[1] = __floats2half2_rn(hv.z, hv.w);
        } else {
            for (int j = 1; j < L; ++j) {
                uint2 u = *(const uint2*)(hbase + (size_t)j * nstride
                                          + (size_t)grow * NDIM + c4 * 4);
                __half2 x0 = __builtin_bit_cast(__half2, u.x);
                __half2 x1 = __builtin_bit_cast(__half2, u.y);
                float2 f0 = __half22float2(x0), f1 = __half22float2(x1);
                hv.x += f0.x; hv.y += f0.y; hv.z += f1.x; hv.w += f1.y;
            }
            *(float4*)(jk + (size_t)grow * NDIM + c4 * 4) = hv;
        }
    }
}

extern "C" void kernel_launch(void* const* d_in, const int* in_sizes, int n_in,
                              void* d_out, int out_size, void* d_ws, size_t ws_size,
                              hipStream_t stream) {
    const float* x     = (const float*)d_in[0];
    const int*   src   = (const int*)  d_in[1];
    const int*   dst   = (const int*)  d_in[2];
    const float* W1    = (const float*)d_in[3];
    const float* b1    = (const float*)d_in[4];
    const float* gamma = (const float*)d_in[5];
    const float* beta  = (const float*)d_in[6];
    const float* mean  = (const float*)d_in[7];
    const float* var   = (const float*)d_in[8];
    const float* W2    = (const float*)d_in[9];
    const float* b2    = (const float*)d_in[10];

    int N = in_sizes[0] / NDIM;
    int E = in_sizes[1];
    int L = in_sizes[3] / (NDIM * NDIM);
    int NBb = (N + 255) >> 8;            // buckets of 256 nodes
    int n4 = N * NDIM / 4;
    float* out = (float*)d_out;
    size_t ns = (size_t)N * NDIM;

    char* w = (char*)d_ws;
    size_t off = 0;
    auto carve = [&](size_t bytes) -> void* {
        void* p = w + off;
        off += (bytes + 255) & ~(size_t)255;
        return p;
    };
    __half* h16     = (__half*)carve((size_t)(L + 1) * ns * 2);  // x16, h1..hL chain
    int*    ssrc    = (int*)   carve((size_t)E * 4);
    unsigned int* packed = (unsigned int*)carve((size_t)NBb * CAP * 4);
    int*    offs    = (int*)   carve((size_t)N * 4);
    int*    ends    = (int*)   carve((size_t)N * 4);
    int*    bcnt    = (int*)   carve((size_t)(MAXNB + 1) * 4);
    _Float16* Wpk   = (_Float16*)carve((size_t)L * 2 * 16 * 64 * 8 * 2);  // hi/lo packed frags
    float*  b1f     = (float*) carve((size_t)L * NDIM * 4);

    prep_kernel<<<2 * L + (n4 + 255) / 256, 256, 0, stream>>>(
        x, h16, n4, W1, b1, gamma, beta, mean, var, W2, Wpk, b1f, L,
        bcnt, NBb + 1);
    bucket_scatter_kernel<<<256, 256, 0, stream>>>(src, dst, bcnt, packed, E, NBb);
    bucket_csr_kernel<<<NBb, 256, 0, stream>>>(packed, bcnt, ssrc, offs, ends, N);

    int NB16 = (N + 15) / 16;
    for (int l = 0; l < L; ++l) {
        gin_layer_kernel<<<NB16, 64, 0, stream>>>(
            h16 + (size_t)l * ns, h16 + (size_t)(l + 1) * ns, out, h16,
            offs, ends, ssrc,
            Wpk + (size_t)(l * 2 + 0) * 16 * 64 * 8,
            Wpk + (size_t)(l * 2 + 1) * 16 * 64 * 8,
            b1f + (size_t)l * NDIM, b2 + (size_t)l * NDIM,
            N, L, (l < L - 1) ? 1 : 0, (l == L - 1) ? 1 : 0);
    }
}